// Round 5
// baseline (441.008 us; speedup 1.0000x reference)
//
#include <hip/hip_runtime.h>

#define B_ 32
#define S_ 2048
#define H_ 1024

typedef __attribute__((ext_vector_type(8))) short short8;
typedef __attribute__((ext_vector_type(4))) float f32x4;
typedef __attribute__((ext_vector_type(16))) float f32x16;
typedef __attribute__((ext_vector_type(4))) unsigned short u16x4;

__device__ __forceinline__ unsigned short f2bf(float f) {
    unsigned u = __builtin_bit_cast(unsigned, f);
    u += 0x7FFFu + ((u >> 16) & 1u);
    return (unsigned short)(u >> 16);
}
__device__ __forceinline__ unsigned pk2(float x, float y) {
    return (unsigned)f2bf(x) | ((unsigned)f2bf(y) << 16);
}
__device__ __forceinline__ float bf2f(unsigned short u) {
    unsigned x = ((unsigned)u) << 16;
    return __builtin_bit_cast(float, x);
}
__device__ __forceinline__ void gload16(const void* g, void* l) {
    __builtin_amdgcn_global_load_lds((const __attribute__((address_space(1))) void*)g,
                                     (__attribute__((address_space(3))) void*)l, 16, 0, 0);
}

#define WAITV(nstr) asm volatile("s_waitcnt vmcnt(" nstr ")" ::: "memory")
#define BAR() __builtin_amdgcn_s_barrier()

// ---------- enc fp32 -> bf16 ----------
__global__ void k_cvt(const float* __restrict__ in, uint4* __restrict__ out, int ngroups) {
    int i = blockIdx.x * blockDim.x + threadIdx.x;
    int stride = gridDim.x * blockDim.x;
    for (; i < ngroups; i += stride) {
        const float4* p = (const float4*)in + (size_t)i * 2;
        float4 x = p[0], y = p[1];
        out[i] = make_uint4(pk2(x.x, x.y), pk2(x.z, x.w), pk2(y.x, y.y), pk2(y.z, y.w));
    }
}

// ---------- prep: Wh (K,N) fp32 -> WhT (N,K) bf16 ----------
__global__ void k_whT(const float* __restrict__ Wh, unsigned short* __restrict__ whT) {
    __shared__ float tile[64][65];
    int k0 = blockIdx.x * 64, n0 = blockIdx.y * 64;
    int tx = threadIdx.x, ty = threadIdx.y; // (64,4)
    #pragma unroll
    for (int i = 0; i < 16; ++i) {
        int r = ty + i * 4;
        tile[r][tx] = Wh[(size_t)(k0 + r) * H_ + n0 + tx];
    }
    __syncthreads();
    #pragma unroll
    for (int i = 0; i < 16; ++i) {
        int r = ty + i * 4;
        whT[(size_t)(n0 + r) * H_ + k0 + tx] = f2bf(tile[tx][r]);
    }
}

// ---------- prep: decp[b][n] = ds[b]@Ws[:,n] + bs[n] + bh[n]; 4 batches/block ----------
__global__ void k_decp(const float* __restrict__ ds, const float* __restrict__ Ws,
                       const float* __restrict__ bs, const float* __restrict__ bh,
                       float* __restrict__ decp) {
    __shared__ float sd[4][1024];
    int tid = threadIdx.x;
    int n = blockIdx.x * 256 + tid;
    int b0 = blockIdx.y * 4;
    for (int i = tid; i < 4 * 1024; i += 256) sd[i >> 10][i & 1023] = ds[b0 * H_ + i];
    __syncthreads();
    float a0 = 0.f, a1 = 0.f, a2 = 0.f, a3 = 0.f;
    for (int k = 0; k < H_; ++k) {
        float w = Ws[(size_t)k * H_ + n];
        a0 += sd[0][k] * w; a1 += sd[1][k] * w;
        a2 += sd[2][k] * w; a3 += sd[3][k] * w;
    }
    float bias = bs[n] + bh[n];
    decp[(b0 + 0) * H_ + n] = a0 + bias;
    decp[(b0 + 1) * H_ + n] = a1 + bias;
    decp[(b0 + 2) * H_ + n] = a2 + bias;
    decp[(b0 + 3) * H_ + n] = a3 + bias;
}

// ---------- prep: covp[b] = cov[b]@Wc + bc ----------
__global__ void k_covp(const float* __restrict__ cov, const float* __restrict__ Wc,
                       const float* __restrict__ bc, float* __restrict__ covp) {
    int b = blockIdx.x, t = threadIdx.x;
    float p = 0.f;
    for (int s = t; s < S_; s += 256) p += cov[b * S_ + s] * Wc[s];
    for (int off = 32; off; off >>= 1) p += __shfl_down(p, off);
    __shared__ float w[4];
    if ((t & 63) == 0) w[t >> 6] = p;
    __syncthreads();
    if (t == 0) covp[b] = w[0] + w[1] + w[2] + w[3] + bc[0];
}

// ---------- main GEMM: 256x256 tile, 8 waves, 32x32x16 MFMA, reg read-ahead ----------
// LDS: ring of 4 half-buffers x 32KB (A 16KB | B 16KB); half h = k in [h*32, h*32+32).
// Chunk (1KB) = 32 rows x 16 k, lane-linear: lane l <-> (row l&31, k (l>>5)*8..+8)
// == exactly one 32x32x16 A/B fragment slice -> gload_lds dest & ds_read both linear.
// Pipeline: phases p = (h, ks). Phase p: issue ds_reads for p+1 (into the OTHER
// static reg set), issue one stage, then 8 MFMA on the current set. Compiler's
// dependence-driven lgkmcnt only waits the current set -> read latency hides
// under MFMA. One barrier + counted vmcnt(4) per half; never drains till tail.
__global__ __launch_bounds__(512, 2) void k_gemm_32(
    const unsigned short* __restrict__ A, const unsigned short* __restrict__ Bm,
    const float* __restrict__ decp, const float* __restrict__ covp,
    const float* __restrict__ V, float* __restrict__ scores)
{
    __shared__ char lds[131072];

    int bid = blockIdx.x;
    // bijective XCD-chunked swizzle (1024 % 8 == 0)
    int xcd = bid & 7, local = bid >> 3;
    int T = xcd * 128 + local;
    int tile_m = T >> 2, tile_n = T & 3;
    size_t row0 = (size_t)tile_m * 256;
    int n0 = tile_n * 256;

    int t = threadIdx.x, lane = t & 63, wid = t >> 6; // 8 waves
    int wm = wid >> 2, wn = wid & 3;                  // 2 x 4 wave grid, 128x64/wave
    int lr = lane & 31, lk = (lane >> 5) * 8;

    // staging: wave wid owns row-block wid (rows wid*32..+32) for both A and B
    const unsigned short* gA = A + (row0 + (size_t)(wid * 32) + lr) * H_ + lk;
    const unsigned short* gB = Bm + ((size_t)(n0 + wid * 32 + lr)) * H_ + lk;

    f32x16 acc[4][2] = {};
    short8 af0[4], bf0[2], af1[4], bf1[2];

    auto stA = [&](int h) {
        char* lb = lds + (h & 3) * 32768;
        gload16(gA + h * 32, lb + (2 * wid) * 1024);
        gload16(gA + h * 32 + 16, lb + (2 * wid + 1) * 1024);
    };
    auto stB = [&](int h) {
        char* lb = lds + (h & 3) * 32768 + 16384;
        gload16(gB + h * 32, lb + (2 * wid) * 1024);
        gload16(gB + h * 32 + 16, lb + (2 * wid + 1) * 1024);
    };

    // frag read: A chunk index (wm*4+mf)*2+ks ; B chunk (wn*2+nf)*2+ks
    int aoff = wm * 8 * 1024 + lane * 16;
    int boff = 16384 + wn * 4 * 1024 + lane * 16;

#define LDA(AF, h, ks) do { const char* hb_ = lds + ((h) & 3) * 32768; \
    AF[0] = *(const short8*)(hb_ + aoff + ((ks) + 0) * 1024); \
    AF[1] = *(const short8*)(hb_ + aoff + ((ks) + 2) * 1024); \
    AF[2] = *(const short8*)(hb_ + aoff + ((ks) + 4) * 1024); \
    AF[3] = *(const short8*)(hb_ + aoff + ((ks) + 6) * 1024); } while (0)
#define LDB(BF, h, ks) do { const char* hb_ = lds + ((h) & 3) * 32768; \
    BF[0] = *(const short8*)(hb_ + boff + ((ks) + 0) * 1024); \
    BF[1] = *(const short8*)(hb_ + boff + ((ks) + 2) * 1024); } while (0)
#define MFMA8(AF, BF) do { \
    __builtin_amdgcn_s_setprio(1); \
    _Pragma("unroll") \
    for (int mf_ = 0; mf_ < 4; ++mf_) { \
        acc[mf_][0] = __builtin_amdgcn_mfma_f32_32x32x16_bf16(AF[mf_], BF[0], acc[mf_][0], 0, 0, 0); \
        acc[mf_][1] = __builtin_amdgcn_mfma_f32_32x32x16_bf16(AF[mf_], BF[1], acc[mf_][1], 0, 0, 0); \
    } \
    __builtin_amdgcn_s_setprio(0); } while (0)

    // prologue: halves 0,1,2 in flight (12 loads/thread)
    stA(0); stB(0); stA(1); stB(1); stA(2); stB(2);
    WAITV("4");   // halves 0,1 landed (all waves after barrier)
    BAR();
    LDA(af0, 0, 0); LDB(bf0, 0, 0);

    for (int h = 0; h < 32; ++h) {
        // phase ks0: compute set0, read set1 = (h, ks1)
        LDA(af1, h, 1); LDB(bf1, h, 1);
        if (h < 29) stA(h + 3);
        MFMA8(af0, bf0);
        // phase ks1: compute set1, read set0 = (h+1, ks0)
        if (h < 31) { LDA(af0, h + 1, 0); LDB(bf0, h + 1, 0); }
        if (h < 29) stB(h + 3);
        MFMA8(af1, bf1);
        if (h < 31) {
            if (h >= 28) { WAITV("0"); } else { WAITV("4"); }
            BAR();
        }
    }
#undef LDA
#undef LDB
#undef MFMA8

    // ---- epilogue: tanh + V-dot + 32-lane reduce + atomicAdd ----
    // C/D 32x32: col = lane&31, row = (reg&3) + 8*(reg>>2) + 4*(lane>>5)
    int b = (int)(row0 >> 11); // block fits in one batch (2048 % 256 == 0)
    float cb = covp[b];
    float vv[2], dpv[2];
    #pragma unroll
    for (int nf = 0; nf < 2; ++nf) {
        int c = n0 + wn * 64 + nf * 32 + lr;
        vv[nf] = V[c];
        dpv[nf] = decp[b * H_ + c] + cb;
    }
    int hi4 = (lane >> 5) * 4;
    #pragma unroll
    for (int mf = 0; mf < 4; ++mf) {
        float rs[16];
        #pragma unroll
        for (int r = 0; r < 16; ++r) rs[r] = 0.f;
        #pragma unroll
        for (int nf = 0; nf < 2; ++nf) {
            #pragma unroll
            for (int r = 0; r < 16; ++r) {
                float x = acc[mf][nf][r] + dpv[nf];
                float e = __expf(2.f * x);
                float th = 1.f - 2.f / (e + 1.f); // inf-safe tanh
                rs[r] += th * vv[nf];
            }
        }
        #pragma unroll
        for (int off = 1; off < 32; off <<= 1) {
            #pragma unroll
            for (int r = 0; r < 16; ++r) rs[r] += __shfl_xor(rs[r], off);
        }
        if (lr == 0) {
            size_t rb = row0 + (size_t)wm * 128 + mf * 32 + hi4;
            #pragma unroll
            for (int r = 0; r < 16; ++r)
                atomicAdd(&scores[rb + (r & 3) + 8 * (r >> 2)], rs[r]);
        }
    }
}

// ---------- fallback epilogue (4-wave 16x16 kernel) ----------
__device__ __forceinline__ void score_epilogue(
    f32x4 acc[4][4], int n0, int wm, int wn, int lane, size_t row0,
    const float* __restrict__ decp, const float* __restrict__ covp,
    const float* __restrict__ V, float* __restrict__ scores)
{
    int colb = n0 + wn * 64 + (lane & 15);
    size_t rowg = row0 + (size_t)wm * 64;
    int b = (int)(rowg >> 11);
    float cb = covp[b];
    float vv[4], dp[4];
    #pragma unroll
    for (int n = 0; n < 4; ++n) {
        int c = colb + n * 16;
        vv[n] = V[c];
        dp[n] = decp[b * H_ + c] + cb;
    }
    #pragma unroll
    for (int m = 0; m < 4; ++m) {
        float rs[4] = {0.f, 0.f, 0.f, 0.f};
        #pragma unroll
        for (int n = 0; n < 4; ++n) {
            f32x4 A = acc[m][n];
            #pragma unroll
            for (int j = 0; j < 4; ++j) {
                float x = A[j] + dp[n];
                float e = __expf(2.f * x);
                float th = 1.f - 2.f / (e + 1.f);
                rs[j] += th * vv[n];
            }
        }
        #pragma unroll
        for (int off = 1; off < 16; off <<= 1) {
            #pragma unroll
            for (int j = 0; j < 4; ++j) rs[j] += __shfl_xor(rs[j], off);
        }
        if ((lane & 15) == 0) {
            size_t r = rowg + m * 16 + (lane >> 4) * 4;
            #pragma unroll
            for (int j = 0; j < 4; ++j) atomicAdd(&scores[r + j], rs[j]);
        }
    }
}

// ---------- fallback GEMM (fp32 A reg-staged, 128^2) ----------
__global__ __launch_bounds__(256, 2) void k_gemm_stage32(
    const float* __restrict__ enc, const unsigned short* __restrict__ whT,
    const float* __restrict__ decp, const float* __restrict__ covp,
    const float* __restrict__ V, float* __restrict__ scores)
{
    __shared__ uint4 lds[2][1024];
    int bid = blockIdx.x;
    int xcd = bid & 7, idx = bid >> 3;
    int tile_m = xcd * 64 + (idx >> 3);
    int tile_n = idx & 7;
    int t = threadIdx.x, lane = t & 63, wid = t >> 6;
    int wm = wid >> 1, wn = wid & 1;
    size_t row0 = (size_t)tile_m * 128;
    int n0 = tile_n * 128;
    int c0 = t, c1 = t + 256;
    int blk0 = c0 >> 6, l0 = c0 & 63, r0 = blk0 * 16 + (l0 & 15), ks0 = l0 >> 4;
    int blk1 = c1 >> 6, l1 = c1 & 63, r1 = blk1 * 16 + (l1 & 15), ks1 = l1 >> 4;
    const float* pa0 = enc + (row0 + r0) * H_ + ks0 * 8;
    const float* pa1 = enc + (row0 + r1) * H_ + ks1 * 8;
    const unsigned short* pb0 = whT + (size_t)(n0 + r0) * H_ + ks0 * 8;
    const unsigned short* pb1 = whT + (size_t)(n0 + r1) * H_ + ks1 * 8;
    f32x4 acc[4][4] = {};
    float4 a0x, a0y, a1x, a1y;
    uint4 b0, b1;
    auto LOAD = [&](int kt) {
        const float4* q0 = (const float4*)(pa0 + kt * 32);
        a0x = q0[0]; a0y = q0[1];
        const float4* q1 = (const float4*)(pa1 + kt * 32);
        a1x = q1[0]; a1y = q1[1];
        b0 = *(const uint4*)(pb0 + kt * 32);
        b1 = *(const uint4*)(pb1 + kt * 32);
    };
    auto WRITE = [&](int buf) {
        lds[buf][c0] = make_uint4(pk2(a0x.x, a0x.y), pk2(a0x.z, a0x.w),
                                  pk2(a0y.x, a0y.y), pk2(a0y.z, a0y.w));
        lds[buf][c1] = make_uint4(pk2(a1x.x, a1x.y), pk2(a1x.z, a1x.w),
                                  pk2(a1y.x, a1y.y), pk2(a1y.z, a1y.w));
        lds[buf][512 + c0] = b0;
        lds[buf][512 + c1] = b1;
    };
    LOAD(0); WRITE(0); __syncthreads();
    int cur = 0;
    for (int kt = 0; kt < 32; ++kt) {
        if (kt < 31) LOAD(kt + 1);
        const short8* LA = (const short8*)&lds[cur][0];
        const short8* LB = (const short8*)&lds[cur][512];
        short8 af[4], bf[4];
        #pragma unroll
        for (int m = 0; m < 4; ++m) af[m] = LA[(wm * 4 + m) * 64 + lane];
        #pragma unroll
        for (int n = 0; n < 4; ++n) bf[n] = LB[(wn * 4 + n) * 64 + lane];
        #pragma unroll
        for (int m = 0; m < 4; ++m)
            #pragma unroll
            for (int n = 0; n < 4; ++n)
                acc[m][n] = __builtin_amdgcn_mfma_f32_16x16x32_bf16(af[m], bf[n], acc[m][n], 0, 0, 0);
        if (kt < 31) WRITE(cur ^ 1);
        __syncthreads();
        cur ^= 1;
    }
    score_epilogue(acc, n0, wm, wn, lane, row0, decp, covp, V, scores);
}

// ---------- softmax over S per b; writes attn and coverage_new ----------
__global__ void k_softmax(const float* __restrict__ scores, const float* __restrict__ cov,
                          float* __restrict__ out) {
    int b = blockIdx.x, t = threadIdx.x;
    float* attn = out + B_ * H_;
    float* covn = out + B_ * H_ + B_ * S_;
    float v[8];
    float mx = -1e30f;
    #pragma unroll
    for (int i = 0; i < 8; ++i) {
        v[i] = scores[b * S_ + i * 256 + t];
        mx = fmaxf(mx, v[i]);
    }
    for (int off = 32; off; off >>= 1) mx = fmaxf(mx, __shfl_xor(mx, off));
    __shared__ float wsm[4], wss[4];
    if ((t & 63) == 0) wsm[t >> 6] = mx;
    __syncthreads();
    mx = fmaxf(fmaxf(wsm[0], wsm[1]), fmaxf(wsm[2], wsm[3]));
    float sum = 0.f;
    #pragma unroll
    for (int i = 0; i < 8; ++i) { v[i] = __expf(v[i] - mx); sum += v[i]; }
    for (int off = 32; off; off >>= 1) sum += __shfl_xor(sum, off);
    if ((t & 63) == 0) wss[t >> 6] = sum;
    __syncthreads();
    sum = wss[0] + wss[1] + wss[2] + wss[3];
    float inv = 1.f / sum;
    #pragma unroll
    for (int i = 0; i < 8; ++i) {
        int s = i * 256 + t;
        float a = v[i] * inv;
        attn[b * S_ + s] = a;
        covn[b * S_ + s] = cov[b * S_ + s] + a;
    }
}

// ---------- context from bf16 enc ----------
__global__ void k_context_bf(const unsigned short* __restrict__ encBF,
                             const float* __restrict__ attn, float* __restrict__ ctx) {
    int b = blockIdx.y, chunk = blockIdx.x; // 16 chunks x 128 s
    int t = threadIdx.x;
    __shared__ float sa[128];
    int s0 = chunk * 128;
    if (t < 128) sa[t] = attn[b * S_ + s0 + t];
    __syncthreads();
    float4 acc = {0.f, 0.f, 0.f, 0.f};
    const unsigned short* e = encBF + ((size_t)(b * S_ + s0)) * H_ + t * 4;
    #pragma unroll 4
    for (int s = 0; s < 128; ++s) {
        u16x4 x = *(const u16x4*)(e + (size_t)s * H_);
        float a = sa[s];
        acc.x += a * bf2f(x[0]); acc.y += a * bf2f(x[1]);
        acc.z += a * bf2f(x[2]); acc.w += a * bf2f(x[3]);
    }
    float* c = ctx + b * H_ + t * 4;
    atomicAdd(c + 0, acc.x); atomicAdd(c + 1, acc.y);
    atomicAdd(c + 2, acc.z); atomicAdd(c + 3, acc.w);
}

// ---------- context from fp32 enc (fallback) ----------
__global__ void k_context_f32(const float* __restrict__ enc, const float* __restrict__ attn,
                              float* __restrict__ ctx) {
    int b = blockIdx.y, chunk = blockIdx.x;
    int t = threadIdx.x;
    __shared__ float sa[128];
    int s0 = chunk * 128;
    if (t < 128) sa[t] = attn[b * S_ + s0 + t];
    __syncthreads();
    float4 acc = {0.f, 0.f, 0.f, 0.f};
    const float4* e = (const float4*)(enc + ((size_t)b * S_ + s0) * H_) + t;
    #pragma unroll 4
    for (int s = 0; s < 128; ++s) {
        float4 x = e[(size_t)s * (H_ / 4)];
        float a = sa[s];
        acc.x += a * x.x; acc.y += a * x.y; acc.z += a * x.z; acc.w += a * x.w;
    }
    float* c = ctx + b * H_ + t * 4;
    atomicAdd(c + 0, acc.x); atomicAdd(c + 1, acc.y);
    atomicAdd(c + 2, acc.z); atomicAdd(c + 3, acc.w);
}

extern "C" void kernel_launch(void* const* d_in, const int* in_sizes, int n_in,
                              void* d_out, int out_size, void* d_ws, size_t ws_size,
                              hipStream_t stream) {
    (void)in_sizes; (void)n_in; (void)out_size;
    const float* ds  = (const float*)d_in[0];
    const float* enc = (const float*)d_in[1];
    const float* cov = (const float*)d_in[2];
    const float* Wh  = (const float*)d_in[3];
    const float* bh  = (const float*)d_in[4];
    const float* Ws  = (const float*)d_in[5];
    const float* bs  = (const float*)d_in[6];
    const float* V   = (const float*)d_in[7];
    // d_in[8] = bv: softmax-invariant constant -> unused
    const float* Wc  = (const float*)d_in[9];
    const float* bc  = (const float*)d_in[10];
    float* out = (float*)d_out;

    float* ws_scores = (float*)d_ws;                          // 65536 f32
    float* ws_decp   = ws_scores + B_ * S_;                   // 32768 f32
    float* ws_covp   = ws_decp + B_ * H_;                     // 64 f32
    unsigned short* ws_whT = (unsigned short*)(ws_covp + 64); // 1M bf16 (2MB)
    unsigned short* ws_encBF = ws_whT + (size_t)H_ * H_;      // 64M bf16 (128MB)
    const size_t need_full = ((char*)(ws_encBF + (size_t)B_ * S_ * H_)) - (char*)d_ws;

    hipMemsetAsync(ws_scores, 0, B_ * S_ * sizeof(float), stream);
    hipMemsetAsync(out, 0, B_ * H_ * sizeof(float), stream); // context accumulators

    k_whT<<<dim3(16, 16), dim3(64, 4), 0, stream>>>(Wh, ws_whT);
    k_decp<<<dim3(4, 8), 256, 0, stream>>>(ds, Ws, bs, bh, ws_decp);
    k_covp<<<32, 256, 0, stream>>>(cov, Wc, bc, ws_covp);

    if (ws_size >= need_full) {
        k_cvt<<<2048, 256, 0, stream>>>(enc, (uint4*)ws_encBF, (B_ * S_ * H_) / 8);
        k_gemm_32<<<1024, 512, 0, stream>>>(ws_encBF, ws_whT, ws_decp, ws_covp, V, ws_scores);
        k_softmax<<<32, 256, 0, stream>>>(ws_scores, cov, out);
        k_context_bf<<<dim3(16, 32), 256, 0, stream>>>(ws_encBF, out + B_ * H_, out);
    } else {
        k_gemm_stage32<<<4096, 256, 0, stream>>>(enc, ws_whT, ws_decp, ws_covp, V, ws_scores);
        k_softmax<<<32, 256, 0, stream>>>(ws_scores, cov, out);
        k_context_f32<<<dim3(16, 32), 256, 0, stream>>>(enc, out + B_ * H_, out);
    }
}

// Round 6
// 340.031 us; speedup vs baseline: 1.2970x; 1.2970x over previous
//
#include <hip/hip_runtime.h>

#define B_ 32
#define S_ 2048
#define H_ 1024

typedef __attribute__((ext_vector_type(8))) short short8;
typedef __attribute__((ext_vector_type(4))) float f32x4;
typedef __attribute__((ext_vector_type(4))) unsigned short u16x4;

__device__ __forceinline__ unsigned short f2bf(float f) {
    unsigned u = __builtin_bit_cast(unsigned, f);
    u += 0x7FFFu + ((u >> 16) & 1u);
    return (unsigned short)(u >> 16);
}
__device__ __forceinline__ unsigned pk2(float x, float y) {
    return (unsigned)f2bf(x) | ((unsigned)f2bf(y) << 16);
}
__device__ __forceinline__ float bf2f(unsigned short u) {
    unsigned x = ((unsigned)u) << 16;
    return __builtin_bit_cast(float, x);
}
__device__ __forceinline__ void gload16(const void* g, void* l) {
    __builtin_amdgcn_global_load_lds((const __attribute__((address_space(1))) void*)g,
                                     (__attribute__((address_space(3))) void*)l, 16, 0, 0);
}

#define WAITV(nstr) asm volatile("s_waitcnt vmcnt(" nstr ")" ::: "memory")
#define BAR() __builtin_amdgcn_s_barrier()

// ---------- enc fp32 -> bf16 ----------
__global__ void k_cvt(const float* __restrict__ in, uint4* __restrict__ out, int ngroups) {
    int i = blockIdx.x * blockDim.x + threadIdx.x;
    int stride = gridDim.x * blockDim.x;
    for (; i < ngroups; i += stride) {
        const float4* p = (const float4*)in + (size_t)i * 2;
        float4 x = p[0], y = p[1];
        out[i] = make_uint4(pk2(x.x, x.y), pk2(x.z, x.w), pk2(y.x, y.y), pk2(y.z, y.w));
    }
}

// ---------- prep: Wh (K,N) fp32 -> WhT (N,K) bf16 ----------
__global__ void k_whT(const float* __restrict__ Wh, unsigned short* __restrict__ whT) {
    __shared__ float tile[64][65];
    int k0 = blockIdx.x * 64, n0 = blockIdx.y * 64;
    int tx = threadIdx.x, ty = threadIdx.y; // (64,4)
    #pragma unroll
    for (int i = 0; i < 16; ++i) {
        int r = ty + i * 4;
        tile[r][tx] = Wh[(size_t)(k0 + r) * H_ + n0 + tx];
    }
    __syncthreads();
    #pragma unroll
    for (int i = 0; i < 16; ++i) {
        int r = ty + i * 4;
        whT[(size_t)(n0 + r) * H_ + k0 + tx] = f2bf(tile[tx][r]);
    }
}

// ---------- prep: decp[b][n] = ds[b]@Ws[:,n] + bs[n] + bh[n] ----------
__global__ void k_decp(const float* __restrict__ ds, const float* __restrict__ Ws,
                       const float* __restrict__ bs, const float* __restrict__ bh,
                       float* __restrict__ decp) {
    int n = blockIdx.x * 256 + threadIdx.x;
    int b = blockIdx.y;
    float a0 = 0.f, a1 = 0.f, a2 = 0.f, a3 = 0.f;
    for (int h = 0; h < H_; h += 4) {
        a0 += ds[b * H_ + h + 0] * Ws[(size_t)(h + 0) * H_ + n];
        a1 += ds[b * H_ + h + 1] * Ws[(size_t)(h + 1) * H_ + n];
        a2 += ds[b * H_ + h + 2] * Ws[(size_t)(h + 2) * H_ + n];
        a3 += ds[b * H_ + h + 3] * Ws[(size_t)(h + 3) * H_ + n];
    }
    decp[b * H_ + n] = a0 + a1 + a2 + a3 + bs[n] + bh[n];
}

// ---------- prep: covp[b] = cov[b]@Wc + bc ----------
__global__ void k_covp(const float* __restrict__ cov, const float* __restrict__ Wc,
                       const float* __restrict__ bc, float* __restrict__ covp) {
    int b = blockIdx.x, t = threadIdx.x;
    float p = 0.f;
    for (int s = t; s < S_; s += 256) p += cov[b * S_ + s] * Wc[s];
    for (int off = 32; off; off >>= 1) p += __shfl_down(p, off);
    __shared__ float w[4];
    if ((t & 63) == 0) w[t >> 6] = p;
    __syncthreads();
    if (t == 0) covp[b] = w[0] + w[1] + w[2] + w[3] + bc[0];
}

// ---------- shared epilogue: tanh + V-dot + 16-lane reduce + atomicAdd ----------
// wave tile 64x64 at (row0 + wm*64, n0 + wn*64); acc[m][n] 16x16 frags.
__device__ __forceinline__ void score_epilogue(
    f32x4 acc[4][4], int n0, int wm, int wn, int lane, size_t row0,
    const float* __restrict__ decp, const float* __restrict__ covp,
    const float* __restrict__ V, float* __restrict__ scores)
{
    int colb = n0 + wn * 64 + (lane & 15);
    size_t rowg = row0 + (size_t)wm * 64;
    int b = (int)(rowg >> 11); // / S_
    float cb = covp[b];
    float vv[4], dp[4];
    #pragma unroll
    for (int n = 0; n < 4; ++n) {
        int c = colb + n * 16;
        vv[n] = V[c];
        dp[n] = decp[b * H_ + c] + cb;
    }
    #pragma unroll
    for (int m = 0; m < 4; ++m) {
        float rs[4] = {0.f, 0.f, 0.f, 0.f};
        #pragma unroll
        for (int n = 0; n < 4; ++n) {
            f32x4 A = acc[m][n];
            #pragma unroll
            for (int j = 0; j < 4; ++j) {
                float x = A[j] + dp[n];
                float e = __expf(2.f * x);
                float th = 1.f - 2.f / (e + 1.f); // inf-safe tanh
                rs[j] += th * vv[n];
            }
        }
        #pragma unroll
        for (int off = 1; off < 16; off <<= 1) {
            #pragma unroll
            for (int j = 0; j < 4; ++j) rs[j] += __shfl_xor(rs[j], off);
        }
        if ((lane & 15) == 0) {
            size_t r = rowg + m * 16 + (lane >> 4) * 4;
            #pragma unroll
            for (int j = 0; j < 4; ++j) atomicAdd(&scores[r + j], rs[j]);
        }
    }
}

// ---------- main GEMM: 256x256 tile, 16 waves (4/SIMD), BK=32, ring-4 counted vmcnt ----
// Identical pipeline to the round-3 kernel (ring of 4 x 32KB halves, vmcnt(4),
// one barrier per half, stage h+3 mid-iter); ONLY change: 16 waves of 64x64
// instead of 8 waves of 128x64 -> 4 waves/SIMD for latency hiding, acc 64 regs.
// LDS chunk (1KB) = 16 rows x 32 k, lane-linear: lane l <-> (row 16c+(l&15),
// k (l>>4)*8..+8). Wave wid stages A chunk wid and B chunk wid (1+1 gload16).
__global__ __launch_bounds__(1024, 4) void k_gemm_16w(
    const unsigned short* __restrict__ A, const unsigned short* __restrict__ Bm,
    const float* __restrict__ decp, const float* __restrict__ covp,
    const float* __restrict__ V, float* __restrict__ scores)
{
    __shared__ char lds[131072]; // ring of 4 x (A 16KB | B 16KB)

    int bid = blockIdx.x;
    // bijective XCD-chunked swizzle (1024 % 8 == 0)
    int xcd = bid & 7, local = bid >> 3;
    int T = xcd * 128 + local;
    int tile_m = T >> 2, tile_n = T & 3;
    size_t row0 = (size_t)tile_m * 256;
    int n0 = tile_n * 256;

    int t = threadIdx.x, lane = t & 63, wid = t >> 6; // 16 waves
    int wm = wid >> 2, wn = wid & 3;                  // 4 x 4 wave grid, 64x64/wave
    int lrow = lane & 15, lk = (lane >> 4) * 8;

    // staging: wave wid owns A chunk wid (rows wid*16..+16) and B chunk wid
    const unsigned short* gA = A + (row0 + (size_t)(wid * 16) + lrow) * H_ + lk;
    const unsigned short* gB = Bm + ((size_t)(n0 + wid * 16 + lrow)) * H_ + lk;

    f32x4 acc[4][4] = {};

    auto stage = [&](int h) {
        char* lb = lds + (h & 3) * 32768;
        gload16(gA + h * 32, lb + wid * 1024);
        gload16(gB + h * 32, lb + 16384 + wid * 1024);
    };

    int aoff = wm * 4 * 1024 + lane * 16;
    int boff = 16384 + wn * 4 * 1024 + lane * 16;

    auto body = [&](int h, bool pf) {
        const char* base = lds + (h & 3) * 32768;
        short8 af[4], bf[4];
        #pragma unroll
        for (int m = 0; m < 4; ++m) af[m] = *(const short8*)(base + aoff + m * 1024);
        #pragma unroll
        for (int n = 0; n < 4; ++n) bf[n] = *(const short8*)(base + boff + n * 1024);
        if (pf) stage(h + 3);
        __builtin_amdgcn_s_setprio(1);
        #pragma unroll
        for (int m = 0; m < 4; ++m)
            #pragma unroll
            for (int n = 0; n < 4; ++n)
                acc[m][n] = __builtin_amdgcn_mfma_f32_16x16x32_bf16(af[m], bf[n], acc[m][n], 0, 0, 0);
        __builtin_amdgcn_s_setprio(0);
    };

    // prologue: halves 0,1,2 in flight (6 loads/thread)
    stage(0); stage(1); stage(2);

    for (int h = 0; h < 29; ++h) {
        WAITV("4");            // half h landed; h+1,h+2 (4 loads) in flight
        BAR();
        body(h, true);         // stages half h+3 mid-body
    }
    WAITV("4"); BAR(); body(29, false);   // 30,31 in flight (4 loads)
    WAITV("2"); BAR(); body(30, false);   // 31 in flight (2 loads)
    WAITV("0"); BAR(); body(31, false);

    score_epilogue(acc, n0, wm, wn, lane, row0, decp, covp, V, scores);
}

// ---------- fallback GEMM (fp32 A reg-staged, 128^2) ----------
__global__ __launch_bounds__(256, 2) void k_gemm_stage32(
    const float* __restrict__ enc, const unsigned short* __restrict__ whT,
    const float* __restrict__ decp, const float* __restrict__ covp,
    const float* __restrict__ V, float* __restrict__ scores)
{
    __shared__ uint4 lds[2][1024];
    int bid = blockIdx.x;
    int xcd = bid & 7, idx = bid >> 3;
    int tile_m = xcd * 64 + (idx >> 3);
    int tile_n = idx & 7;
    int t = threadIdx.x, lane = t & 63, wid = t >> 6;
    int wm = wid >> 1, wn = wid & 1;
    size_t row0 = (size_t)tile_m * 128;
    int n0 = tile_n * 128;
    int c0 = t, c1 = t + 256;
    int blk0 = c0 >> 6, l0 = c0 & 63, r0 = blk0 * 16 + (l0 & 15), ks0 = l0 >> 4;
    int blk1 = c1 >> 6, l1 = c1 & 63, r1 = blk1 * 16 + (l1 & 15), ks1 = l1 >> 4;
    const float* pa0 = enc + (row0 + r0) * H_ + ks0 * 8;
    const float* pa1 = enc + (row0 + r1) * H_ + ks1 * 8;
    const unsigned short* pb0 = whT + (size_t)(n0 + r0) * H_ + ks0 * 8;
    const unsigned short* pb1 = whT + (size_t)(n0 + r1) * H_ + ks1 * 8;
    f32x4 acc[4][4] = {};
    float4 a0x, a0y, a1x, a1y;
    uint4 b0, b1;
    auto LOAD = [&](int kt) {
        const float4* q0 = (const float4*)(pa0 + kt * 32);
        a0x = q0[0]; a0y = q0[1];
        const float4* q1 = (const float4*)(pa1 + kt * 32);
        a1x = q1[0]; a1y = q1[1];
        b0 = *(const uint4*)(pb0 + kt * 32);
        b1 = *(const uint4*)(pb1 + kt * 32);
    };
    auto WRITE = [&](int buf) {
        lds[buf][c0] = make_uint4(pk2(a0x.x, a0x.y), pk2(a0x.z, a0x.w),
                                  pk2(a0y.x, a0y.y), pk2(a0y.z, a0y.w));
        lds[buf][c1] = make_uint4(pk2(a1x.x, a1x.y), pk2(a1x.z, a1x.w),
                                  pk2(a1y.x, a1y.y), pk2(a1y.z, a1y.w));
        lds[buf][512 + c0] = b0;
        lds[buf][512 + c1] = b1;
    };
    LOAD(0); WRITE(0); __syncthreads();
    int cur = 0;
    for (int kt = 0; kt < 32; ++kt) {
        if (kt < 31) LOAD(kt + 1);
        const short8* LA = (const short8*)&lds[cur][0];
        const short8* LB = (const short8*)&lds[cur][512];
        short8 af[4], bf[4];
        #pragma unroll
        for (int m = 0; m < 4; ++m) af[m] = LA[(wm * 4 + m) * 64 + lane];
        #pragma unroll
        for (int n = 0; n < 4; ++n) bf[n] = LB[(wn * 4 + n) * 64 + lane];
        #pragma unroll
        for (int m = 0; m < 4; ++m)
            #pragma unroll
            for (int n = 0; n < 4; ++n)
                acc[m][n] = __builtin_amdgcn_mfma_f32_16x16x32_bf16(af[m], bf[n], acc[m][n], 0, 0, 0);
        if (kt < 31) WRITE(cur ^ 1);
        __syncthreads();
        cur ^= 1;
    }
    score_epilogue(acc, n0, wm, wn, lane, row0, decp, covp, V, scores);
}

// ---------- softmax over S per b; writes attn and coverage_new ----------
__global__ void k_softmax(const float* __restrict__ scores, const float* __restrict__ cov,
                          float* __restrict__ out) {
    int b = blockIdx.x, t = threadIdx.x;
    float* attn = out + B_ * H_;
    float* covn = out + B_ * H_ + B_ * S_;
    float v[8];
    float mx = -1e30f;
    #pragma unroll
    for (int i = 0; i < 8; ++i) {
        v[i] = scores[b * S_ + i * 256 + t];
        mx = fmaxf(mx, v[i]);
    }
    for (int off = 32; off; off >>= 1) mx = fmaxf(mx, __shfl_xor(mx, off));
    __shared__ float wsm[4], wss[4];
    if ((t & 63) == 0) wsm[t >> 6] = mx;
    __syncthreads();
    mx = fmaxf(fmaxf(wsm[0], wsm[1]), fmaxf(wsm[2], wsm[3]));
    float sum = 0.f;
    #pragma unroll
    for (int i = 0; i < 8; ++i) { v[i] = __expf(v[i] - mx); sum += v[i]; }
    for (int off = 32; off; off >>= 1) sum += __shfl_xor(sum, off);
    if ((t & 63) == 0) wss[t >> 6] = sum;
    __syncthreads();
    sum = wss[0] + wss[1] + wss[2] + wss[3];
    float inv = 1.f / sum;
    #pragma unroll
    for (int i = 0; i < 8; ++i) {
        int s = i * 256 + t;
        float a = v[i] * inv;
        attn[b * S_ + s] = a;
        covn[b * S_ + s] = cov[b * S_ + s] + a;
    }
}

// ---------- context from bf16 enc ----------
__global__ void k_context_bf(const unsigned short* __restrict__ encBF,
                             const float* __restrict__ attn, float* __restrict__ ctx) {
    int b = blockIdx.y, chunk = blockIdx.x; // 16 chunks x 128 s
    int t = threadIdx.x;
    __shared__ float sa[128];
    int s0 = chunk * 128;
    if (t < 128) sa[t] = attn[b * S_ + s0 + t];
    __syncthreads();
    float4 acc = {0.f, 0.f, 0.f, 0.f};
    const unsigned short* e = encBF + ((size_t)(b * S_ + s0)) * H_ + t * 4;
    #pragma unroll 4
    for (int s = 0; s < 128; ++s) {
        u16x4 x = *(const u16x4*)(e + (size_t)s * H_);
        float a = sa[s];
        acc.x += a * bf2f(x[0]); acc.y += a * bf2f(x[1]);
        acc.z += a * bf2f(x[2]); acc.w += a * bf2f(x[3]);
    }
    float* c = ctx + b * H_ + t * 4;
    atomicAdd(c + 0, acc.x); atomicAdd(c + 1, acc.y);
    atomicAdd(c + 2, acc.z); atomicAdd(c + 3, acc.w);
}

// ---------- context from fp32 enc (fallback) ----------
__global__ void k_context_f32(const float* __restrict__ enc, const float* __restrict__ attn,
                              float* __restrict__ ctx) {
    int b = blockIdx.y, chunk = blockIdx.x;
    int t = threadIdx.x;
    __shared__ float sa[128];
    int s0 = chunk * 128;
    if (t < 128) sa[t] = attn[b * S_ + s0 + t];
    __syncthreads();
    float4 acc = {0.f, 0.f, 0.f, 0.f};
    const float4* e = (const float4*)(enc + ((size_t)b * S_ + s0) * H_) + t;
    #pragma unroll 4
    for (int s = 0; s < 128; ++s) {
        float4 x = e[(size_t)s * (H_ / 4)];
        float a = sa[s];
        acc.x += a * x.x; acc.y += a * x.y; acc.z += a * x.z; acc.w += a * x.w;
    }
    float* c = ctx + b * H_ + t * 4;
    atomicAdd(c + 0, acc.x); atomicAdd(c + 1, acc.y);
    atomicAdd(c + 2, acc.z); atomicAdd(c + 3, acc.w);
}

extern "C" void kernel_launch(void* const* d_in, const int* in_sizes, int n_in,
                              void* d_out, int out_size, void* d_ws, size_t ws_size,
                              hipStream_t stream) {
    (void)in_sizes; (void)n_in; (void)out_size;
    const float* ds  = (const float*)d_in[0];
    const float* enc = (const float*)d_in[1];
    const float* cov = (const float*)d_in[2];
    const float* Wh  = (const float*)d_in[3];
    const float* bh  = (const float*)d_in[4];
    const float* Ws  = (const float*)d_in[5];
    const float* bs  = (const float*)d_in[6];
    const float* V   = (const float*)d_in[7];
    // d_in[8] = bv: softmax-invariant constant -> unused
    const float* Wc  = (const float*)d_in[9];
    const float* bc  = (const float*)d_in[10];
    float* out = (float*)d_out;

    float* ws_scores = (float*)d_ws;                          // 65536 f32
    float* ws_decp   = ws_scores + B_ * S_;                   // 32768 f32
    float* ws_covp   = ws_decp + B_ * H_;                     // 64 f32
    unsigned short* ws_whT = (unsigned short*)(ws_covp + 64); // 1M bf16 (2MB)
    unsigned short* ws_encBF = ws_whT + (size_t)H_ * H_;      // 64M bf16 (128MB)
    const size_t need_full = ((char*)(ws_encBF + (size_t)B_ * S_ * H_)) - (char*)d_ws;

    hipMemsetAsync(ws_scores, 0, B_ * S_ * sizeof(float), stream);
    hipMemsetAsync(out, 0, B_ * H_ * sizeof(float), stream); // context accumulators

    k_whT<<<dim3(16, 16), dim3(64, 4), 0, stream>>>(Wh, ws_whT);
    k_decp<<<dim3(4, 32), 256, 0, stream>>>(ds, Ws, bs, bh, ws_decp);
    k_covp<<<32, 256, 0, stream>>>(cov, Wc, bc, ws_covp);

    if (ws_size >= need_full) {
        k_cvt<<<2048, 256, 0, stream>>>(enc, (uint4*)ws_encBF, (B_ * S_ * H_) / 8);
        k_gemm_16w<<<1024, 1024, 0, stream>>>(ws_encBF, ws_whT, ws_decp, ws_covp, V, ws_scores);
        k_softmax<<<32, 256, 0, stream>>>(ws_scores, cov, out);
        k_context_bf<<<dim3(16, 32), 256, 0, stream>>>(ws_encBF, out + B_ * H_, out);
    } else {
        k_gemm_stage32<<<4096, 256, 0, stream>>>(enc, ws_whT, ws_decp, ws_covp, V, ws_scores);
        k_softmax<<<32, 256, 0, stream>>>(ws_scores, cov, out);
        k_context_f32<<<dim3(16, 32), 256, 0, stream>>>(enc, out + B_ * H_, out);
    }
}